// Round 1
// baseline (319.563 us; speedup 1.0000x reference)
//
#include <hip/hip_runtime.h>
#include <hip/hip_bf16.h>

// B=4, L=S=2048, D_MODEL=512, H=8, E=64.
// Pipeline (all bf16 MFMA with fp32 accum):
//   1) cvt inputs f32->bf16, weights f32->bf16 transposed [N][K]
//   2) GEMM projections -> Qh [bh][l][e] (pre-scaled 1/8), Kh [bh][s][e], Vt [bh][e][s]
//   3) flash attention (swapped mfma(K,Q), online softmax, P via per-wave LDS) -> Ao [b*l][h*e]
//   4) GEMM output projection + bias -> d_out fp32
// Workspace usage: 7*8MB + 2MB = ~58 MB.

typedef __attribute__((ext_vector_type(8))) short bf8_t;
typedef __attribute__((ext_vector_type(4))) float f4_t;

#define D_MODEL 512
#define HEADS 8
#define EDIM 64
#define LSEQ 2048
#define NBATCH 4
#define MTOT (NBATCH * LSEQ) /* 8192 */

static __device__ __forceinline__ unsigned short f2bf(float f) {
  union { float f; unsigned int u; } x;
  x.f = f;
  unsigned int u = x.u;
  u += 0x7FFFu + ((u >> 16) & 1u);  // RNE
  return (unsigned short)(u >> 16);
}

__global__ void cvt_kernel(const float* __restrict__ in, unsigned short* __restrict__ out, int n4) {
  int i = blockIdx.x * blockDim.x + threadIdx.x;
  if (i >= n4) return;
  float4 v = ((const float4*)in)[i];
  ushort4 o;
  o.x = f2bf(v.x); o.y = f2bf(v.y); o.z = f2bf(v.z); o.w = f2bf(v.w);
  ((ushort4*)out)[i] = o;
}

// Wt[n*512 + k] = W[k*512 + n]  (bf16)
__global__ void wt_cvt_kernel(const float* __restrict__ W, unsigned short* __restrict__ Wt) {
  int idx = blockIdx.x * blockDim.x + threadIdx.x;
  int n = idx >> 9;
  int k = idx & 511;
  Wt[(size_t)idx] = f2bf(W[(size_t)k * D_MODEL + n]);
}

// C = A[M][K] * Bt[N][K]^T + bias. 128x128 tile, BK=32, 4 waves (2x2), 4x4 frags/wave.
// MODE 0: Q -> [bh][l][e] bf16, scaled by 0.125 (after bias)
// MODE 1: K -> [bh][s][e] bf16
// MODE 2: V -> [bh][e][s] bf16 (transposed)
// MODE 3: O -> fp32 [M][512]
template <int MODE>
__global__ __launch_bounds__(256) void gemm_bt(const unsigned short* __restrict__ A,
                                               const unsigned short* __restrict__ Bt,
                                               const float* __restrict__ bias,
                                               void* __restrict__ Cout, int K) {
  __shared__ alignas(16) unsigned short lA[128 * 32];
  __shared__ alignas(16) unsigned short lB[128 * 32];
  const int m0 = blockIdx.x * 128;
  const int n0 = blockIdx.y * 128;
  const int t = threadIdx.x;
  const int lane = t & 63;
  const int w = t >> 6;
  const int wr = w >> 1, wc = w & 1;
  const int r = lane & 15, g = lane >> 4;

  f4_t acc[4][4] = {};

  for (int k0 = 0; k0 < K; k0 += 32) {
#pragma unroll
    for (int i = 0; i < 2; ++i) {
      int c = t + i * 256;          // 512 16B chunks per 128x32 tile
      int row = c >> 2;
      int cb = (c & 3) * 16;        // byte offset within the 64B row
      const char* ga = (const char*)(A + (size_t)(m0 + row) * K + k0) + cb;
      const char* gb = (const char*)(Bt + (size_t)(n0 + row) * K + k0) + cb;
      __builtin_amdgcn_global_load_lds((const __attribute__((address_space(1))) void*)ga,
                                       (__attribute__((address_space(3))) void*)((char*)lA + c * 16),
                                       16, 0, 0);
      __builtin_amdgcn_global_load_lds((const __attribute__((address_space(1))) void*)gb,
                                       (__attribute__((address_space(3))) void*)((char*)lB + c * 16),
                                       16, 0, 0);
    }
    __syncthreads();

    bf8_t af[4], bfv[4];
#pragma unroll
    for (int mi = 0; mi < 4; ++mi)
      af[mi] = *(const bf8_t*)(lA + (wr * 64 + mi * 16 + r) * 32 + g * 8);
#pragma unroll
    for (int ni = 0; ni < 4; ++ni)
      bfv[ni] = *(const bf8_t*)(lB + (wc * 64 + ni * 16 + r) * 32 + g * 8);
#pragma unroll
    for (int mi = 0; mi < 4; ++mi)
#pragma unroll
      for (int ni = 0; ni < 4; ++ni)
        acc[mi][ni] = __builtin_amdgcn_mfma_f32_16x16x32_bf16(af[mi], bfv[ni], acc[mi][ni], 0, 0, 0);
    __syncthreads();
  }

#pragma unroll
  for (int mi = 0; mi < 4; ++mi)
#pragma unroll
    for (int ni = 0; ni < 4; ++ni) {
      const int coln = n0 + wc * 64 + ni * 16 + r;
      const float bv = bias[coln];
#pragma unroll
      for (int j = 0; j < 4; ++j) {
        const int rowm = m0 + wr * 64 + mi * 16 + g * 4 + j;
        float v = acc[mi][ni][j] + bv;
        if (MODE == 0 || MODE == 1) {
          if (MODE == 0) v *= 0.125f;
          const int b = rowm >> 11, li = rowm & 2047;
          const int h = coln >> 6, e = coln & 63;
          ((unsigned short*)Cout)[(((size_t)(b * HEADS + h) * LSEQ + li) << 6) + e] = f2bf(v);
        } else if (MODE == 2) {
          const int b = rowm >> 11, s = rowm & 2047;
          const int h = coln >> 6, e = coln & 63;
          ((unsigned short*)Cout)[(((size_t)(b * HEADS + h) * EDIM + e) << 11) + s] = f2bf(v);
        } else {
          ((float*)Cout)[(size_t)rowm * D_MODEL + coln] = v;
        }
      }
    }
}

// Flash attention. Grid (L/64, BH), block 256 = 4 independent waves, 16 q-rows each.
// Swapped QK^T: St[s][q] = mfma(A=K rows, B=Q^T). Online softmax per q (col). P staged
// through per-wave padded LDS tile [16 q][32+8 s] to form the PV B-fragment.
// PV: Ot[e][q] = mfma(A=Vt rows, B=P^T).
__global__ __launch_bounds__(256) void flash_attn(const unsigned short* __restrict__ Qh,
                                                  const unsigned short* __restrict__ Kh,
                                                  const unsigned short* __restrict__ Vt,
                                                  unsigned short* __restrict__ Ao) {
  __shared__ alignas(16) unsigned short lP[4][16][40];
  const int t = threadIdx.x;
  const int lane = t & 63;
  const int w = t >> 6;
  const int r = lane & 15, g = lane >> 4;
  const int bh = blockIdx.y;
  const int q0 = blockIdx.x * 64 + w * 16;

  const size_t qbase = ((size_t)bh * LSEQ + q0 + r) * EDIM;
  const bf8_t qf0 = *(const bf8_t*)(Qh + qbase + g * 8);
  const bf8_t qf1 = *(const bf8_t*)(Qh + qbase + 32 + g * 8);

  float m_run = -1e30f, l_run = 0.f;
  f4_t oacc[4] = {};

  for (int s0 = 0; s0 < LSEQ; s0 += 32) {
    f4_t sa[2];
#pragma unroll
    for (int st = 0; st < 2; ++st) {
      const size_t kb = ((size_t)bh * LSEQ + s0 + st * 16 + r) * EDIM;
      const bf8_t kf0 = *(const bf8_t*)(Kh + kb + g * 8);
      const bf8_t kf1 = *(const bf8_t*)(Kh + kb + 32 + g * 8);
      f4_t z = {0.f, 0.f, 0.f, 0.f};
      z = __builtin_amdgcn_mfma_f32_16x16x32_bf16(kf0, qf0, z, 0, 0, 0);
      z = __builtin_amdgcn_mfma_f32_16x16x32_bf16(kf1, qf1, z, 0, 0, 0);
      sa[st] = z;
    }
    // per-q (column) tile max over the 32 s values
    float tm = -1e30f;
#pragma unroll
    for (int st = 0; st < 2; ++st)
#pragma unroll
      for (int j = 0; j < 4; ++j) tm = fmaxf(tm, sa[st][j]);
    tm = fmaxf(tm, __shfl_xor(tm, 16));
    tm = fmaxf(tm, __shfl_xor(tm, 32));
    const float m_new = fmaxf(m_run, tm);
    const float alpha = __expf(m_run - m_new);

    float rs = 0.f;
    unsigned short pb[2][4];
#pragma unroll
    for (int st = 0; st < 2; ++st)
#pragma unroll
      for (int j = 0; j < 4; ++j) {
        const float p = __expf(sa[st][j] - m_new);
        rs += p;
        pb[st][j] = f2bf(p);
      }
    rs += __shfl_xor(rs, 16);
    rs += __shfl_xor(rs, 32);
    l_run = l_run * alpha + rs;
    m_run = m_new;
#pragma unroll
    for (int et = 0; et < 4; ++et) {
      oacc[et][0] *= alpha; oacc[et][1] *= alpha;
      oacc[et][2] *= alpha; oacc[et][3] *= alpha;
    }
    // stage P tile: lane holds q=r, s_local = st*16 + 4g + j
#pragma unroll
    for (int st = 0; st < 2; ++st) {
      ushort4 pv;
      pv.x = pb[st][0]; pv.y = pb[st][1]; pv.z = pb[st][2]; pv.w = pb[st][3];
      *(ushort4*)(&lP[w][r][st * 16 + g * 4]) = pv;
    }
    // PV: B-frag = P[q=r][s_local = 8g+j]
    const bf8_t pf = *(const bf8_t*)(&lP[w][r][g * 8]);
#pragma unroll
    for (int et = 0; et < 4; ++et) {
      const size_t vb = ((size_t)bh * EDIM + et * 16 + r) * LSEQ + s0 + g * 8;
      const bf8_t vf = *(const bf8_t*)(Vt + vb);
      oacc[et] = __builtin_amdgcn_mfma_f32_16x16x32_bf16(vf, pf, oacc[et], 0, 0, 0);
    }
  }

  const float inv = 1.f / l_run;
  const int b = bh >> 3, h = bh & 7;
#pragma unroll
  for (int et = 0; et < 4; ++et) {
    ushort4 ov;
    ov.x = f2bf(oacc[et][0] * inv);
    ov.y = f2bf(oacc[et][1] * inv);
    ov.z = f2bf(oacc[et][2] * inv);
    ov.w = f2bf(oacc[et][3] * inv);
    const size_t addr = ((size_t)(b * LSEQ + q0 + r)) * D_MODEL + h * EDIM + et * 16 + g * 4;
    *(ushort4*)(Ao + addr) = ov;
  }
}

extern "C" void kernel_launch(void* const* d_in, const int* in_sizes, int n_in,
                              void* d_out, int out_size, void* d_ws, size_t ws_size,
                              hipStream_t stream) {
  const float* queries = (const float*)d_in[0];
  const float* keys    = (const float*)d_in[1];
  const float* values  = (const float*)d_in[2];
  const float* Wq = (const float*)d_in[3];
  const float* bq = (const float*)d_in[4];
  const float* Wk = (const float*)d_in[5];
  const float* bk = (const float*)d_in[6];
  const float* Wv = (const float*)d_in[7];
  const float* bv = (const float*)d_in[8];
  const float* Wo = (const float*)d_in[9];
  const float* bo = (const float*)d_in[10];

  char* ws = (char*)d_ws;
  const size_t XSZ = (size_t)MTOT * D_MODEL * 2;  // 8 MB
  unsigned short* Xq  = (unsigned short*)(ws + 0 * XSZ);
  unsigned short* Xk  = (unsigned short*)(ws + 1 * XSZ);
  unsigned short* Xv  = (unsigned short*)(ws + 2 * XSZ);
  unsigned short* Qh  = (unsigned short*)(ws + 3 * XSZ);
  unsigned short* Kh  = (unsigned short*)(ws + 4 * XSZ);
  unsigned short* Vt  = (unsigned short*)(ws + 5 * XSZ);
  unsigned short* Ao  = (unsigned short*)(ws + 6 * XSZ);
  unsigned short* Wqt = (unsigned short*)(ws + 7 * XSZ);
  unsigned short* Wkt = Wqt + 512 * 512;
  unsigned short* Wvt = Wkt + 512 * 512;
  unsigned short* Wot = Wvt + 512 * 512;

  const int n4 = MTOT * D_MODEL / 4;  // 1,048,576
  cvt_kernel<<<n4 / 256, 256, 0, stream>>>(queries, Xq, n4);
  cvt_kernel<<<n4 / 256, 256, 0, stream>>>(keys, Xk, n4);
  cvt_kernel<<<n4 / 256, 256, 0, stream>>>(values, Xv, n4);

  wt_cvt_kernel<<<(512 * 512) / 256, 256, 0, stream>>>(Wq, Wqt);
  wt_cvt_kernel<<<(512 * 512) / 256, 256, 0, stream>>>(Wk, Wkt);
  wt_cvt_kernel<<<(512 * 512) / 256, 256, 0, stream>>>(Wv, Wvt);
  wt_cvt_kernel<<<(512 * 512) / 256, 256, 0, stream>>>(Wo, Wot);

  dim3 gg(MTOT / 128, D_MODEL / 128);  // (64, 4)
  gemm_bt<0><<<gg, 256, 0, stream>>>(Xq, Wqt, bq, Qh, D_MODEL);
  gemm_bt<1><<<gg, 256, 0, stream>>>(Xk, Wkt, bk, Kh, D_MODEL);
  gemm_bt<2><<<gg, 256, 0, stream>>>(Xv, Wvt, bv, Vt, D_MODEL);

  flash_attn<<<dim3(LSEQ / 64, NBATCH * HEADS), 256, 0, stream>>>(Qh, Kh, Vt, Ao);

  gemm_bt<3><<<gg, 256, 0, stream>>>(Ao, Wot, bo, d_out, D_MODEL);
}

// Round 2
// 166.137 us; speedup vs baseline: 1.9235x; 1.9235x over previous
//
#include <hip/hip_runtime.h>
#include <hip/hip_bf16.h>

// B=4, L=S=2048, D_MODEL=512, H=8, E=64.
// Pipeline (all bf16 MFMA with fp32 accum):
//   1) cvt inputs f32->bf16, weights f32->bf16 transposed [N][K]
//   2) GEMM projections -> Qh [bh][l][e] (pre-scaled 1/8), Kh [bh][s][e], Vt [bh][e][s]
//   3) flash attention: 4 waves x QBLK=32, KVBLK=64, mfma 32x32x16, LDS-staged K/V
//      (double-buffered, XOR-swizzled via pre-swizzled global source), swapped QK^T,
//      in-register softmax + P-refragment via shfl_xor(32), defer-max THR=8
//   4) GEMM output projection + bias -> d_out fp32

typedef __attribute__((ext_vector_type(8))) short bf8_t;
typedef __attribute__((ext_vector_type(4))) float f4_t;
typedef __attribute__((ext_vector_type(16))) float f16_t;
typedef __attribute__((ext_vector_type(4))) unsigned int u32x4;

#define D_MODEL 512
#define HEADS 8
#define EDIM 64
#define LSEQ 2048
#define NBATCH 4
#define MTOT (NBATCH * LSEQ) /* 8192 */

static __device__ __forceinline__ unsigned short f2bf(float f) {
  union { float f; unsigned int u; } x;
  x.f = f;
  unsigned int u = x.u;
  u += 0x7FFFu + ((u >> 16) & 1u);  // RNE
  return (unsigned short)(u >> 16);
}

static __device__ __forceinline__ unsigned int pack2bf(float a, float b) {
  union { __hip_bfloat162 h; unsigned int u; } c;
  c.h.x = __float2bfloat16(a);
  c.h.y = __float2bfloat16(b);
  return c.u;  // low 16 = a, high 16 = b  (compiler can fuse to v_cvt_pk_bf16_f32)
}

__global__ void cvt_kernel(const float* __restrict__ in, unsigned short* __restrict__ out, int n4) {
  int i = blockIdx.x * blockDim.x + threadIdx.x;
  if (i >= n4) return;
  float4 v = ((const float4*)in)[i];
  ushort4 o;
  o.x = f2bf(v.x); o.y = f2bf(v.y); o.z = f2bf(v.z); o.w = f2bf(v.w);
  ((ushort4*)out)[i] = o;
}

// Wt[n*512 + k] = W[k*512 + n]  (bf16)
__global__ void wt_cvt_kernel(const float* __restrict__ W, unsigned short* __restrict__ Wt) {
  int idx = blockIdx.x * blockDim.x + threadIdx.x;
  int n = idx >> 9;
  int k = idx & 511;
  Wt[(size_t)idx] = f2bf(W[(size_t)k * D_MODEL + n]);
}

// C = A[M][K] * Bt[N][K]^T + bias. 128x128 tile, BK=32, 4 waves (2x2), 4x4 frags/wave.
// MODE 0: Q -> [bh][l][e] bf16, scaled by 0.125 (after bias)
// MODE 1: K -> [bh][s][e] bf16
// MODE 2: V -> [bh][e][s] bf16 (transposed)
// MODE 3: O -> fp32 [M][512]
template <int MODE>
__global__ __launch_bounds__(256) void gemm_bt(const unsigned short* __restrict__ A,
                                               const unsigned short* __restrict__ Bt,
                                               const float* __restrict__ bias,
                                               void* __restrict__ Cout, int K) {
  __shared__ alignas(16) unsigned short lA[128 * 32];
  __shared__ alignas(16) unsigned short lB[128 * 32];
  const int m0 = blockIdx.x * 128;
  const int n0 = blockIdx.y * 128;
  const int t = threadIdx.x;
  const int lane = t & 63;
  const int w = t >> 6;
  const int wr = w >> 1, wc = w & 1;
  const int r = lane & 15, g = lane >> 4;

  f4_t acc[4][4] = {};

  for (int k0 = 0; k0 < K; k0 += 32) {
#pragma unroll
    for (int i = 0; i < 2; ++i) {
      int c = t + i * 256;          // 512 16B chunks per 128x32 tile
      int row = c >> 2;
      int cb = (c & 3) * 16;        // byte offset within the 64B row
      const char* ga = (const char*)(A + (size_t)(m0 + row) * K + k0) + cb;
      const char* gb = (const char*)(Bt + (size_t)(n0 + row) * K + k0) + cb;
      __builtin_amdgcn_global_load_lds((const __attribute__((address_space(1))) void*)ga,
                                       (__attribute__((address_space(3))) void*)((char*)lA + c * 16),
                                       16, 0, 0);
      __builtin_amdgcn_global_load_lds((const __attribute__((address_space(1))) void*)gb,
                                       (__attribute__((address_space(3))) void*)((char*)lB + c * 16),
                                       16, 0, 0);
    }
    __syncthreads();

    bf8_t af[4], bfv[4];
#pragma unroll
    for (int mi = 0; mi < 4; ++mi)
      af[mi] = *(const bf8_t*)(lA + (wr * 64 + mi * 16 + r) * 32 + g * 8);
#pragma unroll
    for (int ni = 0; ni < 4; ++ni)
      bfv[ni] = *(const bf8_t*)(lB + (wc * 64 + ni * 16 + r) * 32 + g * 8);
#pragma unroll
    for (int mi = 0; mi < 4; ++mi)
#pragma unroll
      for (int ni = 0; ni < 4; ++ni)
        acc[mi][ni] = __builtin_amdgcn_mfma_f32_16x16x32_bf16(af[mi], bfv[ni], acc[mi][ni], 0, 0, 0);
    __syncthreads();
  }

#pragma unroll
  for (int mi = 0; mi < 4; ++mi)
#pragma unroll
    for (int ni = 0; ni < 4; ++ni) {
      const int coln = n0 + wc * 64 + ni * 16 + r;
      const float bv = bias[coln];
#pragma unroll
      for (int j = 0; j < 4; ++j) {
        const int rowm = m0 + wr * 64 + mi * 16 + g * 4 + j;
        float v = acc[mi][ni][j] + bv;
        if (MODE == 0 || MODE == 1) {
          if (MODE == 0) v *= 0.125f;
          const int b = rowm >> 11, li = rowm & 2047;
          const int h = coln >> 6, e = coln & 63;
          ((unsigned short*)Cout)[(((size_t)(b * HEADS + h) * LSEQ + li) << 6) + e] = f2bf(v);
        } else if (MODE == 2) {
          const int b = rowm >> 11, s = rowm & 2047;
          const int h = coln >> 6, e = coln & 63;
          ((unsigned short*)Cout)[(((size_t)(b * HEADS + h) * EDIM + e) << 11) + s] = f2bf(v);
        } else {
          ((float*)Cout)[(size_t)rowm * D_MODEL + coln] = v;
        }
      }
    }
}

// ---------------- flash attention ----------------
// Grid (LSEQ/128, BH=32), block 256 = 4 waves, QBLK=32 q-rows per wave, KVBLK=64.
// K tile [64 s][64 e], V tile [64 e][64 s] staged in LDS (double-buffered) via
// global_load_lds with pre-swizzled source: LDS chunk (row, col) holds global
// chunk (row, col ^ (row&7)); reads apply the same XOR -> conflict-free b128.
// Swapped QK^T: S[s][q] = mfma(A=K, B=Q^T); C col = q = lane&31, row = s.
// PV: O[e][q] = mfma(A=V^T, B=P^T).

__device__ __forceinline__ void stage_tile(const unsigned short* __restrict__ Kh,
                                           const unsigned short* __restrict__ Vt,
                                           unsigned short* ldsK, unsigned short* ldsV,
                                           int bh, int s0) {
  const int t = threadIdx.x;
#pragma unroll
  for (int ii = 0; ii < 2; ++ii) {
    int c = t + ii * 256;            // 512 chunks of 16B per 8KB tile
    int row = c >> 3, col = c & 7;
    int colp = col ^ (row & 7);      // involution: pre-swizzled source
    const char* gk = (const char*)(Kh + ((size_t)bh * LSEQ + s0 + row) * EDIM + colp * 8);
    __builtin_amdgcn_global_load_lds((const __attribute__((address_space(1))) void*)gk,
                                     (__attribute__((address_space(3))) void*)((char*)ldsK + c * 16),
                                     16, 0, 0);
    const char* gv = (const char*)(Vt + ((size_t)bh * EDIM + row) * LSEQ + s0 + colp * 8);
    __builtin_amdgcn_global_load_lds((const __attribute__((address_space(1))) void*)gv,
                                     (__attribute__((address_space(3))) void*)((char*)ldsV + c * 16),
                                     16, 0, 0);
  }
}

__global__ __launch_bounds__(256) void flash_attn(const unsigned short* __restrict__ Qh,
                                                  const unsigned short* __restrict__ Kh,
                                                  const unsigned short* __restrict__ Vt,
                                                  unsigned short* __restrict__ Ao) {
  __shared__ alignas(16) unsigned short lsK[2][64 * 64];
  __shared__ alignas(16) unsigned short lsV[2][64 * 64];

  const int t = threadIdx.x;
  const int lane = t & 63;
  const int w = t >> 6;
  const int qn = lane & 31;        // q column (and s/e row for A-frags)
  const int hi = lane >> 5;        // k-group select
  const int bh = blockIdx.y;
  const int q0w = blockIdx.x * 128 + w * 32;

  // Q B-fragments: B[k=e][n=q], n = lane&31, k = 16*kst + 8*hi + j
  bf8_t qf[4];
#pragma unroll
  for (int kst = 0; kst < 4; ++kst)
    qf[kst] = *(const bf8_t*)(Qh + ((size_t)bh * LSEQ + q0w + qn) * EDIM + kst * 16 + hi * 8);

  float m_run = -1e30f, l_run = 0.f;
  f16_t oacc[2];
#pragma unroll
  for (int eh = 0; eh < 2; ++eh)
#pragma unroll
    for (int r = 0; r < 16; ++r) oacc[eh][r] = 0.f;

  stage_tile(Kh, Vt, lsK[0], lsV[0], bh, 0);
  __syncthreads();

  int cur = 0;
  for (int kt = 0; kt < LSEQ / 64; ++kt) {
    if (kt + 1 < LSEQ / 64)
      stage_tile(Kh, Vt, lsK[cur ^ 1], lsV[cur ^ 1], bh, (kt + 1) * 64);

    // ---- QK^T ----
    bf8_t kf[2][4];
#pragma unroll
    for (int sh = 0; sh < 2; ++sh)
#pragma unroll
      for (int kst = 0; kst < 4; ++kst) {
        const int row = 32 * sh + qn;
        const int ch = (2 * kst + hi) ^ (row & 7);
        kf[sh][kst] = *(const bf8_t*)(&lsK[cur][row * 64 + ch * 8]);
      }
    f16_t sacc[2];
#pragma unroll
    for (int sh = 0; sh < 2; ++sh)
#pragma unroll
      for (int r = 0; r < 16; ++r) sacc[sh][r] = 0.f;
#pragma unroll
    for (int sh = 0; sh < 2; ++sh)
#pragma unroll
      for (int kst = 0; kst < 4; ++kst)
        sacc[sh] = __builtin_amdgcn_mfma_f32_32x32x16_bf16(kf[sh][kst], qf[kst], sacc[sh], 0, 0, 0);

    // ---- online softmax (per-lane: 32 values, all same q; partner lane l^32 has rest) ----
    float tm = -1e30f;
#pragma unroll
    for (int sh = 0; sh < 2; ++sh)
#pragma unroll
      for (int r = 0; r < 16; ++r) tm = fmaxf(tm, sacc[sh][r]);
    tm = fmaxf(tm, __shfl_xor(tm, 32));

    if (__any(tm > m_run + 8.f)) {   // defer-max: rescale only on real growth
      const float m_new = fmaxf(m_run, tm);
      const float alpha = __expf(m_run - m_new);
      l_run *= alpha;
#pragma unroll
      for (int eh = 0; eh < 2; ++eh)
#pragma unroll
        for (int r = 0; r < 16; ++r) oacc[eh][r] *= alpha;
      m_run = m_new;
    }

    float rs = 0.f;
    unsigned int pk[16];
#pragma unroll
    for (int sh = 0; sh < 2; ++sh)
#pragma unroll
      for (int i = 0; i < 8; ++i) {
        const float a = __expf(sacc[sh][2 * i] - m_run);
        const float b = __expf(sacc[sh][2 * i + 1] - m_run);
        rs += a + b;
        pk[sh * 8 + i] = pack2bf(a, b);
      }
    rs += __shfl_xor(rs, 32);
    l_run += rs;

    unsigned int sw[16];
#pragma unroll
    for (int i = 0; i < 16; ++i) sw[i] = __shfl_xor(pk[i], 32);

    // PV B-frags: B[k=s][n=q]; s = 16*t2 + 8*hi + j
    bf8_t pvb[4];
#pragma unroll
    for (int t2 = 0; t2 < 4; ++t2) {
      union { u32x4 u; bf8_t b; } pb;
      pb.u[0] = hi ? sw[4 * t2 + 2] : pk[4 * t2 + 0];
      pb.u[1] = hi ? sw[4 * t2 + 3] : pk[4 * t2 + 1];
      pb.u[2] = hi ? pk[4 * t2 + 2] : sw[4 * t2 + 0];
      pb.u[3] = hi ? pk[4 * t2 + 3] : sw[4 * t2 + 1];
      pvb[t2] = pb.b;
    }

    // ---- PV ----
#pragma unroll
    for (int eh = 0; eh < 2; ++eh)
#pragma unroll
      for (int t2 = 0; t2 < 4; ++t2) {
        const int row = 32 * eh + qn;
        const int ch = (2 * t2 + hi) ^ (row & 7);
        const bf8_t vf = *(const bf8_t*)(&lsV[cur][row * 64 + ch * 8]);
        oacc[eh] = __builtin_amdgcn_mfma_f32_32x32x16_bf16(vf, pvb[t2], oacc[eh], 0, 0, 0);
      }

    __syncthreads();
    cur ^= 1;
  }

  // ---- epilogue: O[e][q] / l_run -> Ao[(b*L + q)][h*64 + e] ----
  const float inv = 1.f / l_run;
  const int b = bh >> 3, h = bh & 7;
#pragma unroll
  for (int eh = 0; eh < 2; ++eh)
#pragma unroll
    for (int k = 0; k < 4; ++k) {
      ushort4 ov;
      ov.x = f2bf(oacc[eh][4 * k + 0] * inv);
      ov.y = f2bf(oacc[eh][4 * k + 1] * inv);
      ov.z = f2bf(oacc[eh][4 * k + 2] * inv);
      ov.w = f2bf(oacc[eh][4 * k + 3] * inv);
      const int e = 32 * eh + 8 * k + 4 * hi;
      *(ushort4*)(Ao + ((size_t)(b * LSEQ + q0w + qn)) * D_MODEL + h * EDIM + e) = ov;
    }
}

extern "C" void kernel_launch(void* const* d_in, const int* in_sizes, int n_in,
                              void* d_out, int out_size, void* d_ws, size_t ws_size,
                              hipStream_t stream) {
  const float* queries = (const float*)d_in[0];
  const float* keys    = (const float*)d_in[1];
  const float* values  = (const float*)d_in[2];
  const float* Wq = (const float*)d_in[3];
  const float* bq = (const float*)d_in[4];
  const float* Wk = (const float*)d_in[5];
  const float* bk = (const float*)d_in[6];
  const float* Wv = (const float*)d_in[7];
  const float* bv = (const float*)d_in[8];
  const float* Wo = (const float*)d_in[9];
  const float* bo = (const float*)d_in[10];

  char* ws = (char*)d_ws;
  const size_t XSZ = (size_t)MTOT * D_MODEL * 2;  // 8 MB
  unsigned short* Xq  = (unsigned short*)(ws + 0 * XSZ);
  unsigned short* Xk  = (unsigned short*)(ws + 1 * XSZ);
  unsigned short* Xv  = (unsigned short*)(ws + 2 * XSZ);
  unsigned short* Qh  = (unsigned short*)(ws + 3 * XSZ);
  unsigned short* Kh  = (unsigned short*)(ws + 4 * XSZ);
  unsigned short* Vt  = (unsigned short*)(ws + 5 * XSZ);
  unsigned short* Ao  = (unsigned short*)(ws + 6 * XSZ);
  unsigned short* Wqt = (unsigned short*)(ws + 7 * XSZ);
  unsigned short* Wkt = Wqt + 512 * 512;
  unsigned short* Wvt = Wkt + 512 * 512;
  unsigned short* Wot = Wvt + 512 * 512;

  const int n4 = MTOT * D_MODEL / 4;  // 1,048,576
  cvt_kernel<<<n4 / 256, 256, 0, stream>>>(queries, Xq, n4);
  cvt_kernel<<<n4 / 256, 256, 0, stream>>>(keys, Xk, n4);
  cvt_kernel<<<n4 / 256, 256, 0, stream>>>(values, Xv, n4);

  wt_cvt_kernel<<<(512 * 512) / 256, 256, 0, stream>>>(Wq, Wqt);
  wt_cvt_kernel<<<(512 * 512) / 256, 256, 0, stream>>>(Wk, Wkt);
  wt_cvt_kernel<<<(512 * 512) / 256, 256, 0, stream>>>(Wv, Wvt);
  wt_cvt_kernel<<<(512 * 512) / 256, 256, 0, stream>>>(Wo, Wot);

  dim3 gg(MTOT / 128, D_MODEL / 128);  // (64, 4)
  gemm_bt<0><<<gg, 256, 0, stream>>>(Xq, Wqt, bq, Qh, D_MODEL);
  gemm_bt<1><<<gg, 256, 0, stream>>>(Xk, Wkt, bk, Kh, D_MODEL);
  gemm_bt<2><<<gg, 256, 0, stream>>>(Xv, Wvt, bv, Vt, D_MODEL);

  flash_attn<<<dim3(LSEQ / 128, NBATCH * HEADS), 256, 0, stream>>>(Qh, Kh, Vt, Ao);

  gemm_bt<3><<<gg, 256, 0, stream>>>(Ao, Wot, bo, d_out, D_MODEL);
}